// Round 1
// baseline (339.688 us; speedup 1.0000x reference)
//
#include <hip/hip_runtime.h>
#include <math.h>

#define LL 128
#define TT 11
#define KK 7
#define NEGV -10000.0f
#define MASK_NEGV -1000000000.0f

// One block per batch element. 128 threads; threads 0..120 own a (y_prev, y)
// pair; threads 0..10 do the final per-y combine. alpha[(L+1) x T] in LDS.
// Score loads for step i+1 are prefetched into registers during step i
// (addresses are alpha-independent), hiding global latency behind the
// sequential DP chain.
__global__ __launch_bounds__(128) void hscrf_fwd(const float* __restrict__ scores,
                                                 const int* __restrict__ mask,
                                                 float* __restrict__ partial) {
    const int b = blockIdx.x;
    const int t = threadIdx.x;

    __shared__ float alpha[(LL + 1) * TT];   // 129*11 floats
    __shared__ float m_part[TT * TT];
    __shared__ float s_part[TT * TT];

    const bool active = (t < TT * TT);
    const int yp = t / TT;        // y_prev (valid when active)
    // y = t - yp*TT (implicit in the strided combine below)

    // alpha row 0: NEG everywhere except start_id = T-1 -> 0
    if (t < TT) alpha[t] = (t == TT - 1) ? 0.0f : NEGV;

    const float* sb = scores + (size_t)b * LL * LL * TT * TT;

    // scores[b][j][i-1][yp][y] for j = i-K+k; thread t indexes the contiguous
    // (yp,y) pane directly.
    float s_reg[KK];
    float s_nxt[KK];
    if (active) {
        const int i = 1;
        #pragma unroll
        for (int k = 0; k < KK; ++k) {
            const int j = i - KK + k;
            if (j >= 0)
                s_reg[k] = sb[((size_t)j * LL + (i - 1)) * (TT * TT) + t];
        }
    }
    __syncthreads();

    for (int i = 1; i <= LL; ++i) {
        // Prefetch scores for step i+1 (no alpha dependency).
        if (active && i < LL) {
            const int inx = i + 1;
            #pragma unroll
            for (int k = 0; k < KK; ++k) {
                const int j = inx - KK + k;
                if (j >= 0)
                    s_nxt[k] = sb[((size_t)j * LL + (inx - 1)) * (TT * TT) + t];
            }
        }

        if (active) {
            // Online logsumexp over the K span starts for this (yp, y).
            float m = MASK_NEGV, s = 0.0f;
            #pragma unroll
            for (int k = 0; k < KK; ++k) {
                const int j = i - KK + k;
                if (j >= 0) {
                    const float x = alpha[j * TT + yp] + s_reg[k];
                    if (x > m) { s = s * __expf(m - x) + 1.0f; m = x; }
                    else       { s += __expf(x - m); }
                }
            }
            m_part[t] = m;
            s_part[t] = s;
        }
        __syncthreads();

        // Combine the 11 y_prev partials for each y; write alpha[i][y].
        if (t < TT) {
            float M = MASK_NEGV, S = 0.0f;
            #pragma unroll
            for (int p = 0; p < TT; ++p) {
                const float pm = m_part[p * TT + t];
                const float ps = s_part[p * TT + t];
                if (pm > M) { S = S * __expf(M - pm) + ps; M = pm; }
                else        { S += ps * __expf(pm - M); }
            }
            alpha[i * TT + t] = M + __logf(S);
        }

        if (active) {
            #pragma unroll
            for (int k = 0; k < KK; ++k) s_reg[k] = s_nxt[k];
        }
        __syncthreads();
    }

    if (t == 0) {
        const int mb = mask[b];                 // in [L/2, L]
        partial[b] = alpha[mb * TT + (TT - 2)]; // stop_id = T-2
    }
}

// Deterministic final sum over the B per-batch results.
__global__ void hscrf_reduce(const float* __restrict__ partial,
                             float* __restrict__ out, int B) {
    if (threadIdx.x == 0) {
        float acc = 0.0f;
        for (int b = 0; b < B; ++b) acc += partial[b];
        out[0] = acc;
    }
}

extern "C" void kernel_launch(void* const* d_in, const int* in_sizes, int n_in,
                              void* d_out, int out_size, void* d_ws, size_t ws_size,
                              hipStream_t stream) {
    const float* scores = (const float*)d_in[0];
    const int*   mask   = (const int*)d_in[1];
    float* out = (float*)d_out;
    float* partial = (float*)d_ws;
    const int B = in_sizes[1];   // 16

    hscrf_fwd<<<B, 128, 0, stream>>>(scores, mask, partial);
    hscrf_reduce<<<1, 64, 0, stream>>>(partial, out, B);
}

// Round 2
// 279.832 us; speedup vs baseline: 1.2139x; 1.2139x over previous
//
#include <hip/hip_runtime.h>
#include <math.h>

#define LL 128
#define TT 11
#define NP (TT * TT)          // 121 (y_prev, y) pairs
#define KK 7
#define NEGV -10000.0f
#define MASK_NEGV -1000000000.0f

// Wave-synchronous LDS fence: single-wave workgroup is lockstep, DS ops
// complete in order, so visibility only needs lgkmcnt(0). Crucially this
// does NOT drain vmcnt, so prefetched global score loads stay in flight.
__device__ __forceinline__ void lds_fence() {
    __builtin_amdgcn_wave_barrier();
    asm volatile("s_waitcnt lgkmcnt(0)" ::: "memory");
    __builtin_amdgcn_wave_barrier();
}

// One wave (64 lanes) per batch element. Lane l owns pair o0 = l and
// o1 = l + 64 (o1 < 121 valid; lanes 57..63's second pair is a harmless
// dummy writing to sp[121..127]). Pair index o = y*11 + y_prev so phase-2
// partials are contiguous per y. Score element index e = y_prev*11 + y.
__global__ __launch_bounds__(64) void hscrf_fwd(const float* __restrict__ scores,
                                                const int* __restrict__ mask,
                                                float* __restrict__ out) {
    const int b = blockIdx.x;
    const int l = threadIdx.x;

    __shared__ float  alpha[(LL + 1) * TT];   // 129 x 11
    __shared__ float2 sp[128];                // phase-1 partials (m, s)

    const int o0 = l;
    const int o1 = l + 64;
    const int o1c = (o1 < NP) ? o1 : 0;       // clamp for address math only

    const int y0 = o0 / TT, yp0 = o0 % TT;
    const int y1 = o1c / TT, yp1 = o1c % TT;
    const int e0 = yp0 * TT + y0;
    const int e1 = yp1 * TT + y1;

    const int mb = mask[b];                   // uniform scalar load, issued early
    const float* sb = scores + (size_t)b * LL * LL * NP;

    // alpha row 0: NEG except start_id = T-1 -> 0
    if (l < TT) alpha[l] = (l == TT - 1) ? 0.0f : NEGV;

    // Sliding alpha window: w[k] holds alpha[i-7+k][yp] during step i
    // (MASK_NEGV until shifted in => masks j<0 terms exactly like the ref).
    float w0[KK], w1[KK];
#pragma unroll
    for (int k = 0; k < KK; ++k) { w0[k] = MASK_NEGV; w1[k] = MASK_NEGV; }

    // Depth-2 prefetch buffers for score panes.
    float cA0[KK], cA1[KK], cB0[KK], cB1[KK];

    auto load_pane = [&](int i, float (&c0)[KK], float (&c1)[KK]) {
        const size_t col = (size_t)(i - 1);
#pragma unroll
        for (int k = 0; k < KK; ++k) {
            int j = i - KK + k;
            int jc = j < 0 ? 0 : j;           // clipped like ref; masked via w
            const size_t base = ((size_t)jc * LL + col) * NP;
            c0[k] = sb[base + e0];
            c1[k] = sb[base + e1];
        }
    };

    load_pane(1, cA0, cA1);
    load_pane(2, cB0, cB1);

    lds_fence();   // alpha row 0 visible

    auto step = [&](int i, float (&c0)[KK], float (&c1)[KK]) {
        // Newest alpha row first: LDS read latency overlaps the k<6 chain.
        const float na0 = alpha[(i - 1) * TT + yp0];
        const float na1 = alpha[(i - 1) * TT + yp1];
#pragma unroll
        for (int k = 0; k < KK - 1; ++k) { w0[k] = w0[k + 1]; w1[k] = w1[k + 1]; }
        w0[KK - 1] = na0;
        w1[KK - 1] = na1;

        // Branch-free online LSE over the 7 span starts, both pairs interleaved.
        float m0 = MASK_NEGV, s0 = 0.0f, m1 = MASK_NEGV, s1 = 0.0f;
#pragma unroll
        for (int k = 0; k < KK; ++k) {
            const float x0 = w0[k] + c0[k];
            const float n0 = fmaxf(m0, x0);
            s0 = s0 * __expf(m0 - n0) + __expf(x0 - n0);
            m0 = n0;
            const float x1 = w1[k] + c1[k];
            const float n1 = fmaxf(m1, x1);
            s1 = s1 * __expf(m1 - n1) + __expf(x1 - n1);
            m1 = n1;
        }

        // Refill this buffer for step i+2 NOW so the loads are in flight
        // across both fences (fences only wait lgkmcnt).
        if (i + 2 <= LL) load_pane(i + 2, c0, c1);

        sp[o0] = make_float2(m0, s0);
        sp[o1] = make_float2(m1, s1);        // dummy pairs land in sp[121..127]

        lds_fence();

        // Phase 2: lane y (<11) combines the 11 y_prev partials.
        if (l < TT) {
            float M = MASK_NEGV, S = 0.0f;
#pragma unroll
            for (int p = 0; p < TT; ++p) {
                const float2 v = sp[l * TT + p];
                const float nM = fmaxf(M, v.x);
                S = S * __expf(M - nM) + v.y * __expf(v.x - nM);
                M = nM;
            }
            alpha[i * TT + l] = M + __logf(S);
        }

        lds_fence();
    };

    for (int i = 1; i <= LL; i += 2) {
        step(i, cA0, cA1);
        step(i + 1, cB0, cB1);
    }

    if (l == 0) {
        atomicAdd(out, alpha[mb * TT + (TT - 2)]);   // stop_id = T-2
    }
}

extern "C" void kernel_launch(void* const* d_in, const int* in_sizes, int n_in,
                              void* d_out, int out_size, void* d_ws, size_t ws_size,
                              hipStream_t stream) {
    const float* scores = (const float*)d_in[0];
    const int*   mask   = (const int*)d_in[1];
    float* out = (float*)d_out;
    const int B = in_sizes[1];   // 16

    hipMemsetAsync(out, 0, sizeof(float) * out_size, stream);
    hscrf_fwd<<<B, 64, 0, stream>>>(scores, mask, out);
}

// Round 3
// 249.050 us; speedup vs baseline: 1.3639x; 1.1236x over previous
//
#include <hip/hip_runtime.h>
#include <math.h>

#define LL 128
#define TT 11
#define NP (TT * TT)          // 121 (y, y_prev) pairs
#define KK 7
#define WPB 4                 // independent waves (= batches) per block

#define LOG2E 1.4426950408889634f
#define LN2   0.6931471805599453f
#define NEG2  (-10000.0f * LOG2E)   // ref NEG in base-2 domain
#define MASK2 (-1.0e9f)             // masked terms: exp2 underflows to 0

#if __has_builtin(__builtin_amdgcn_exp2f)
__device__ __forceinline__ float fast_exp2(float x) { return __builtin_amdgcn_exp2f(x); }
#else
__device__ __forceinline__ float fast_exp2(float x) { return __expf(x * LN2); }
#endif
#if __has_builtin(__builtin_amdgcn_logf)
__device__ __forceinline__ float fast_log2(float x) { return __builtin_amdgcn_logf(x); }
#else
__device__ __forceinline__ float fast_log2(float x) { return __logf(x) * LOG2E; }
#endif

// Wave-synchronous LDS fence: single wave is lockstep; DS ops need only
// lgkmcnt. Does NOT drain vmcnt -> prefetched score loads stay in flight.
__device__ __forceinline__ void lds_fence() {
    __builtin_amdgcn_wave_barrier();
    asm volatile("s_waitcnt lgkmcnt(0)" ::: "memory");
    __builtin_amdgcn_wave_barrier();
}

// One wave per batch, WPB independent waves per block (no inter-wave sync;
// each wave has its own LDS slice). Lane l owns pairs o0=l, o1=l+64 with
// o = y*11 + yp. Phase 2: EVERY lane combines the group y = l%11 == its own
// yp0, so next step's alpha arrives in-register; the second pair's alpha
// comes from one ds_bpermute. DP runs in base-2 log domain.
__global__ __launch_bounds__(64 * WPB) void hscrf_fwd(const float* __restrict__ scores,
                                                      const int* __restrict__ mask,
                                                      float* __restrict__ out,
                                                      int n_batch) {
    const int w = threadIdx.x >> 6;
    const int l = threadIdx.x & 63;
    const int b = blockIdx.x * WPB + w;
    if (b >= n_batch) return;              // waves are independent; safe

    __shared__ float2 sp_all[WPB][128];
    float2* sp = sp_all[w];

    const int o1  = l + 64;
    const int o1c = (o1 < NP) ? o1 : 0;    // lanes 57..63: dummy second pair
    const int y0 = l / TT,   yp0 = l % TT;
    const int y1 = o1c / TT, yp1 = o1c % TT;
    const int e0 = yp0 * TT + y0;          // scores pane index [yp][y]
    const int e1 = yp1 * TT + y1;

    const int mb = mask[b];
    const float* sb = scores + (size_t)b * LL * LL * NP;

    // Sliding alpha2 window: w?[k] = alpha2[i-7+k][yp] during step i.
    float w0[KK], w1[KK];
#pragma unroll
    for (int k = 0; k < KK; ++k) { w0[k] = MASK2; w1[k] = MASK2; }
    float na0 = (yp0 == TT - 1) ? 0.0f : NEG2;   // alpha2 row 0
    float na1 = (yp1 == TT - 1) ? 0.0f : NEG2;
    float saved = 0.0f;

    float cA0[KK], cA1[KK], cB0[KK], cB1[KK];    // depth-2 prefetch

    auto load_pane = [&](int i, float (&c0)[KK], float (&c1)[KK]) {
        const size_t col = (size_t)(i - 1);
#pragma unroll
        for (int k = 0; k < KK; ++k) {
            int j = i - KK + k;
            int jc = j < 0 ? 0 : j;              // clipped; masked via window
            const size_t base = ((size_t)jc * LL + col) * NP;
            c0[k] = sb[base + e0];
            c1[k] = sb[base + e1];
        }
    };

    load_pane(1, cA0, cA1);
    load_pane(2, cB0, cB1);

    auto step = [&](int i, float (&c0)[KK], float (&c1)[KK]) {
        // Shift newest alpha2 row into the window (in-register, no LDS).
#pragma unroll
        for (int k = 0; k < KK - 1; ++k) { w0[k] = w0[k + 1]; w1[k] = w1[k + 1]; }
        w0[KK - 1] = na0;
        w1[KK - 1] = na1;

        // Phase 1: max-then-sum LSE over the 7 span starts, both pairs.
        float x0[KK], x1[KK];
#pragma unroll
        for (int k = 0; k < KK; ++k) {
            x0[k] = fmaf(c0[k], LOG2E, w0[k]);
            x1[k] = fmaf(c1[k], LOG2E, w1[k]);
        }
        const float m0 = fmaxf(fmaxf(fmaxf(x0[0], x0[1]), fmaxf(x0[2], x0[3])),
                               fmaxf(fmaxf(x0[4], x0[5]), x0[6]));
        const float m1 = fmaxf(fmaxf(fmaxf(x1[0], x1[1]), fmaxf(x1[2], x1[3])),
                               fmaxf(fmaxf(x1[4], x1[5]), x1[6]));
        float g0[KK], g1[KK];
#pragma unroll
        for (int k = 0; k < KK; ++k) {
            g0[k] = fast_exp2(x0[k] - m0);       // independent exps
            g1[k] = fast_exp2(x1[k] - m1);
        }
        const float s0 = ((g0[0] + g0[1]) + (g0[2] + g0[3])) + ((g0[4] + g0[5]) + g0[6]);
        const float s1 = ((g1[0] + g1[1]) + (g1[2] + g1[3])) + ((g1[4] + g1[5]) + g1[6]);

        sp[l]      = make_float2(m0, s0);
        sp[l + 64] = make_float2(m1, s1);        // dummies land in sp[121..127]

        // Refill this buffer for step i+2 now; loads stay in flight across
        // the fence (fence waits lgkm only).
        if (i + 2 <= LL) load_pane(i + 2, c0, c1);

        lds_fence();

        // Phase 2: every lane combines group y = yp0 (duplicated across
        // lanes with equal l%11; same-address LDS reads broadcast).
        float2 v[TT];
#pragma unroll
        for (int p = 0; p < TT; ++p) v[p] = sp[yp0 * TT + p];

        const float M = fmaxf(
            fmaxf(fmaxf(fmaxf(v[0].x, v[1].x), fmaxf(v[2].x, v[3].x)),
                  fmaxf(fmaxf(v[4].x, v[5].x), fmaxf(v[6].x, v[7].x))),
            fmaxf(fmaxf(v[8].x, v[9].x), v[10].x));
        float tt[TT];
#pragma unroll
        for (int p = 0; p < TT; ++p) tt[p] = v[p].y * fast_exp2(v[p].x - M);
        const float S = ((tt[0] + tt[1]) + (tt[2] + tt[3])) +
                        ((tt[4] + tt[5]) + (tt[6] + tt[7])) +
                        ((tt[8] + tt[9]) + tt[10]);
        const float A2 = M + fast_log2(S);       // alpha2[i][yp0], in-register

        na0 = A2;
        na1 = __int_as_float(__builtin_amdgcn_ds_bpermute(yp1 << 2, __float_as_int(A2)));
        saved = (i == mb) ? A2 : saved;          // capture alpha2[mb][l%11]

        lds_fence();   // free: all lgkm ops already drained by data deps
    };

    for (int i = 1; i <= LL; i += 2) {
        step(i,     cA0, cA1);
        step(i + 1, cB0, cB1);
    }

    if (l == TT - 2) {                           // lane 9: y == stop_id
        atomicAdd(out, saved * LN2);             // back to natural log
    }
}

extern "C" void kernel_launch(void* const* d_in, const int* in_sizes, int n_in,
                              void* d_out, int out_size, void* d_ws, size_t ws_size,
                              hipStream_t stream) {
    const float* scores = (const float*)d_in[0];
    const int*   mask   = (const int*)d_in[1];
    float* out = (float*)d_out;
    const int B = in_sizes[1];   // 16

    hipMemsetAsync(out, 0, sizeof(float) * out_size, stream);
    hscrf_fwd<<<(B + WPB - 1) / WPB, 64 * WPB, 0, stream>>>(scores, mask, out, B);
}